// Round 4
// baseline (1309.288 us; speedup 1.0000x reference)
//
#include <hip/hip_runtime.h>

#define NN 50000
#define EE 500000
#define LL 4

typedef unsigned int u32;

__device__ __forceinline__ float lanebc(float v, int l) {
    return __int_as_float(__builtin_amdgcn_readlane(__float_as_int(v), l));
}

// ---- init: Xf(=out-x) = x copy; zero deg/cursor ----
__global__ __launch_bounds__(256) void k_init(const float* __restrict__ x, float* __restrict__ Xf,
                                              int* __restrict__ deg, int* __restrict__ cursor) {
    for (int i = blockIdx.x * 256 + threadIdx.x; i < NN * 64; i += gridDim.x * 256)
        Xf[i] = x[i];
    for (int i = blockIdx.x * 256 + threadIdx.x; i < NN; i += gridDim.x * 256) {
        deg[i] = 0;
        cursor[i] = 0;
    }
}

// ---- phi[l,b,:] = relu(Lambda[b] @ We1[l] + be1[l]) ----
__global__ __launch_bounds__(128) void k_phi(const float* __restrict__ Lam, const float* __restrict__ We1,
                                             const float* __restrict__ be1, float* __restrict__ phiA) {
    int l = blockIdx.x >> 5, b = blockIdx.x & 31, j = threadIdx.x;
    float acc = be1[l * 128 + j];
    for (int q = 0; q < 8; q++)
        acc = fmaf(Lam[b * 8 + q], We1[l * 1024 + q * 128 + j], acc);
    phiA[l * 4096 + b * 128 + j] = fmaxf(acc, 0.f);
}

// ---- CSR build ----
__global__ __launch_bounds__(256) void k_hist(const int* __restrict__ ei, int* __restrict__ deg) {
    int e = blockIdx.x * 256 + threadIdx.x;
    if (e < EE) {
        int d = ei[EE + e];
        if (d >= 0 && d < NN) atomicAdd(&deg[d], 1);
    }
}

__global__ __launch_bounds__(256) void k_scan1(const int* __restrict__ deg, int* __restrict__ rowptr,
                                               int* __restrict__ bsum) {
    __shared__ int tmp[256];
    int t = threadIdx.x, i = blockIdx.x * 256 + t;
    int v = (i < NN) ? deg[i] : 0;
    tmp[t] = v;
    __syncthreads();
    for (int off = 1; off < 256; off <<= 1) {
        int a = (t >= off) ? tmp[t - off] : 0;
        __syncthreads();
        tmp[t] += a;
        __syncthreads();
    }
    if (i < NN) rowptr[i] = tmp[t] - v;
    if (t == 255) bsum[blockIdx.x] = tmp[255];
}

__global__ __launch_bounds__(256) void k_scan2(const int* __restrict__ bsum, int* __restrict__ boff,
                                               int* __restrict__ rowptr, int nb) {
    __shared__ int tmp[256];
    int t = threadIdx.x;
    int v = (t < nb) ? bsum[t] : 0;
    tmp[t] = v;
    __syncthreads();
    for (int off = 1; off < 256; off <<= 1) {
        int a = (t >= off) ? tmp[t - off] : 0;
        __syncthreads();
        tmp[t] += a;
        __syncthreads();
    }
    if (t < nb) boff[t] = tmp[t] - v;
    if (t == 255) rowptr[NN] = tmp[255];
}

__global__ __launch_bounds__(256) void k_scan3(int* __restrict__ rowptr, const int* __restrict__ boff) {
    int i = blockIdx.x * 256 + threadIdx.x;
    if (i < NN) rowptr[i] += boff[blockIdx.x];
}

__global__ __launch_bounds__(256) void k_scatter(const int* __restrict__ ei, const int* __restrict__ batch,
                                                 const int* __restrict__ rowptr, int* __restrict__ cursor,
                                                 u32* __restrict__ sb, int* __restrict__ eeo) {
    int e = blockIdx.x * 256 + threadIdx.x;
    if (e < EE) {
        int s = ei[e], d = ei[EE + e];
        if (s < 0) s = 0; if (s >= NN) s = NN - 1;
        if (d < 0) d = 0; if (d >= NN) d = NN - 1;
        int pos = rowptr[d] + atomicAdd(&cursor[d], 1);
        if (pos >= 0 && pos < EE) {
            sb[pos] = (u32)s | ((u32)(batch[s] & 31) << 16);
            eeo[pos] = e;
        }
    }
}

// ---- fused per-layer edge pass + z einsum epilogue: one wave per dst node ----
// INM: 0 = z comes from pe broadcast (layer 0), 1 = fp32 plane Zf
template <int INM>
__global__ __launch_bounds__(256) void k_edge(const float* __restrict__ Zf,
                                              const float* __restrict__ pe,
                                              const float* __restrict__ Xf, const float* __restrict__ eat,
                                              const int* __restrict__ rowptr, const u32* __restrict__ sb,
                                              const int* __restrict__ eeo,
                                              const float* __restrict__ phiL, const float* __restrict__ WeeL,
                                              const float* __restrict__ beeL,
                                              const float* __restrict__ WgL, const float* __restrict__ bgL,
                                              const float* __restrict__ WpL, const float* __restrict__ bpL,
                                              float* __restrict__ Hf,
                                              float* __restrict__ ZfO,
                                              double* __restrict__ stats) {
    __shared__ float sphi[32 * 128];
    __shared__ float sWp[256];
    __shared__ float sbp[16];
    if (blockIdx.x == 0) stats[threadIdx.x] = 0.0;   // zero BN stats for this layer
    for (int t = threadIdx.x; t < 4096; t += 256) sphi[t] = phiL[t];
    if (threadIdx.x < 256) sWp[threadIdx.x] = WpL[threadIdx.x];
    if (threadIdx.x < 16) sbp[threadIdx.x] = bpL[threadIdx.x];
    const int lane = threadIdx.x & 63;
    const int wid = threadIdx.x >> 6;
    const int hlo = lane >> 3;        // 0..7
    const int pp = lane & 7;          // 0..7
    const int h16 = lane & 15;        // Wg output index owned by this lane
    const int g16 = lane & 48;        // group base for the Wg reduce
    float wee[16], wgr[16];
#pragma unroll
    for (int k = 0; k < 16; k++) {
        wee[k] = WeeL[k * 64 + lane];
        wgr[k] = WgL[(g16 + k) * 16 + h16];
    }
    const float beev = beeL[lane];
    const float bgr = bgL[h16];
    __syncthreads();
    for (int n = blockIdx.x * 4 + wid; n < NN; n += gridDim.x * 4) {
        float zd0, zd1;
        if (INM == 0) { zd0 = zd1 = pe[n * 8 + pp]; }
        else { zd0 = Zf[n * 128 + lane]; zd1 = Zf[n * 128 + 64 + lane]; }
        float accx = Xf[n * 64 + lane];
        float az0 = zd0, az1 = zd1;
        int i0 = rowptr[n], i1 = rowptr[n + 1];
        if (i0 < 0) i0 = 0;
        if (i1 > EE) i1 = EE;
        for (int idx = i0; idx < i1; ++idx) {
            const u32 w = sb[idx];
            const int s = w & 0xffff;
            const int b = (w >> 16) & 31;
            int e = eeo[idx];
            e = (e < 0) ? 0 : ((e >= EE) ? EE - 1 : e);
            float zs0, zs1;
            if (INM == 0) { zs0 = zs1 = pe[s * 8 + pp]; }
            else { zs0 = Zf[s * 128 + lane]; zs1 = Zf[s * 128 + 64 + lane]; }
            // eh[h] = sum_p phi[b,h,p] * zs[h,p] * zd[h,p]  (8-lane group reduce)
            float p0 = sphi[b * 128 + lane] * zs0 * zd0;
            float p1 = sphi[b * 128 + 64 + lane] * zs1 * zd1;
            p0 += __shfl_xor(p0, 1); p1 += __shfl_xor(p1, 1);
            p0 += __shfl_xor(p0, 2); p1 += __shfl_xor(p1, 2);
            p0 += __shfl_xor(p0, 4); p1 += __shfl_xor(p1, 4);
            // ea[j] = bee[j] + edge_attr[e,j] + sum_k eh[k] Wee[k,j]
            float ea = beev + eat[(size_t)e * 64 + lane];
#pragma unroll
            for (int k = 0; k < 8; k++) ea = fmaf(lanebc(p0, k << 3), wee[k], ea);
#pragma unroll
            for (int k = 0; k < 8; k++) ea = fmaf(lanebc(p1, k << 3), wee[8 + k], ea);
            // gate[h] = relu(sum_j ea[j] Wg[j,h] + bg[h]) via 4x16 cross-lane reduce
            float gp = 0.f;
#pragma unroll
            for (int i = 0; i < 16; i++) gp = fmaf(__shfl(ea, g16 + i), wgr[i], gp);
            gp += __shfl_xor(gp, 16);
            gp += __shfl_xor(gp, 32);
            const float gv = fmaxf(gp + bgr, 0.f);    // lane h (h<16) holds gate[h]
            const float glo = __shfl(gv, hlo);
            const float ghi = __shfl(gv, 8 + hlo);
            const float xs = Xf[s * 64 + lane];
            accx += fmaxf(0.f, xs + ea);
            az0 += fmaxf(0.f, zs0 + glo);
            az1 += fmaxf(0.f, zs1 + ghi);
        }
        Hf[n * 64 + lane] = accx;
        // z' [k,p] = sum_h zacc[h,p] * Wp[h,k] + bp[k]
        float r0 = sbp[hlo], r1 = sbp[8 + hlo];
#pragma unroll
        for (int h = 0; h < 8; h++) {
            const float v = __shfl(az0, (h << 3) + pp);
            r0 = fmaf(v, sWp[h * 16 + hlo], r0);
            r1 = fmaf(v, sWp[h * 16 + 8 + hlo], r1);
        }
#pragma unroll
        for (int h = 0; h < 8; h++) {
            const float v = __shfl(az1, (h << 3) + pp);
            r0 = fmaf(v, sWp[(8 + h) * 16 + hlo], r0);
            r1 = fmaf(v, sWp[(8 + h) * 16 + 8 + hlo], r1);
        }
        ZfO[n * 128 + lane] = r0;
        ZfO[n * 128 + 64 + lane] = r1;
    }
}

// ---- t = h @ W1 + b1 (in-place on Hf), fused BN1 stats ----
__global__ __launch_bounds__(256) void k_gemm1(float* Buf, const float* __restrict__ WL,
                                               const float* __restrict__ bL,
                                               double* __restrict__ sum, double* __restrict__ sq) {
    __shared__ float sW[4096];
    __shared__ double red[512];
    for (int t = threadIdx.x; t < 4096; t += 256) sW[t] = WL[t];
    const int lane = threadIdx.x & 63, wid = threadIdx.x >> 6;
    const float bv = bL[lane];
    __syncthreads();
    double s = 0.0, q = 0.0;
    for (int n = blockIdx.x * 4 + wid; n < NN; n += gridDim.x * 4) {
        const float h = Buf[n * 64 + lane];
        float acc = bv;
#pragma unroll
        for (int k = 0; k < 64; k++) acc = fmaf(lanebc(h, k), sW[k * 64 + lane], acc);
        Buf[n * 64 + lane] = acc;
        s += (double)acc;
        q += (double)acc * (double)acc;
    }
    red[threadIdx.x] = s;
    red[256 + threadIdx.x] = q;
    __syncthreads();
    if (threadIdx.x < 64) {
        s = red[threadIdx.x] + red[threadIdx.x + 64] + red[threadIdx.x + 128] + red[threadIdx.x + 192];
        q = red[256 + threadIdx.x] + red[320 + threadIdx.x] + red[384 + threadIdx.x] + red[448 + threadIdx.x];
        atomicAdd(&sum[lane], s);
        atomicAdd(&sq[lane], q);
    }
}

// ---- h2 = relu(BN1(t)) @ W2 + b2 (in-place on Hf), fused BN2 stats ----
__global__ __launch_bounds__(256) void k_gemm2(float* Buf, const float* __restrict__ WL,
                                               const float* __restrict__ bL,
                                               const float* __restrict__ gL, const float* __restrict__ betaL,
                                               const double* __restrict__ s1, const double* __restrict__ q1,
                                               double* __restrict__ sum, double* __restrict__ sq) {
    __shared__ float sW[4096];
    __shared__ double red[512];
    for (int t = threadIdx.x; t < 4096; t += 256) sW[t] = WL[t];
    const int lane = threadIdx.x & 63, wid = threadIdx.x >> 6;
    const float bv = bL[lane];
    const double mu = s1[lane] * (1.0 / NN);
    const double var = q1[lane] * (1.0 / NN) - mu * mu;
    const float inv = rsqrtf(fmaxf((float)var, 0.f) + 1e-5f);
    const float gm = gL[lane] * inv;
    const float ga = betaL[lane] - (float)mu * gm;
    __syncthreads();
    double s = 0.0, q = 0.0;
    for (int n = blockIdx.x * 4 + wid; n < NN; n += gridDim.x * 4) {
        const float v = Buf[n * 64 + lane];
        const float r = fmaxf(fmaf(v, gm, ga), 0.f);
        float acc = bv;
#pragma unroll
        for (int k = 0; k < 64; k++) acc = fmaf(lanebc(r, k), sW[k * 64 + lane], acc);
        Buf[n * 64 + lane] = acc;
        s += (double)acc;
        q += (double)acc * (double)acc;
    }
    red[threadIdx.x] = s;
    red[256 + threadIdx.x] = q;
    __syncthreads();
    if (threadIdx.x < 64) {
        s = red[threadIdx.x] + red[threadIdx.x + 64] + red[threadIdx.x + 128] + red[threadIdx.x + 192];
        q = red[256 + threadIdx.x] + red[320 + threadIdx.x] + red[384 + threadIdx.x] + red[448 + threadIdx.x];
        atomicAdd(&sum[lane], s);
        atomicAdd(&sq[lane], q);
    }
}

// ---- x = BN2(h2) (+relu except last); writes x state into out-x region (fp32) ----
__global__ __launch_bounds__(256) void k_bnout(const float* __restrict__ In, float* __restrict__ Xf,
                                               const double* __restrict__ s2, const double* __restrict__ q2,
                                               const float* __restrict__ gL, const float* __restrict__ bL,
                                               int dorelu) {
    int i = blockIdx.x * 256 + threadIdx.x;
    const int f = i & 63;
    const double mu = s2[f] * (1.0 / NN);
    const double var = q2[f] * (1.0 / NN) - mu * mu;
    const float inv = rsqrtf(fmaxf((float)var, 0.f) + 1e-5f);
    const float gm = gL[f] * inv;
    const float ga = bL[f] - (float)mu * gm;
    for (; i < NN * 64; i += gridDim.x * 256) {
        float o = fmaf(In[i], gm, ga);
        if (dorelu) o = fmaxf(o, 0.f);
        Xf[i] = o;
    }
}

extern "C" void kernel_launch(void* const* d_in, const int* in_sizes, int n_in,
                              void* d_out, int out_size, void* d_ws, size_t ws_size,
                              hipStream_t stream) {
    (void)in_sizes; (void)n_in; (void)out_size; (void)ws_size;
    const float* x    = (const float*)d_in[0];
    const float* pe   = (const float*)d_in[1];
    const float* Lam  = (const float*)d_in[2];
    const float* eat  = (const float*)d_in[3];
    const int*   ei   = (const int*)d_in[4];
    const int*   batch= (const int*)d_in[5];
    const float* We1  = (const float*)d_in[6];
    const float* be1  = (const float*)d_in[7];
    const float* Wee  = (const float*)d_in[8];
    const float* bee  = (const float*)d_in[9];
    const float* W1   = (const float*)d_in[10];
    const float* b1   = (const float*)d_in[11];
    const float* g1   = (const float*)d_in[12];
    const float* bt1  = (const float*)d_in[13];
    const float* W2   = (const float*)d_in[14];
    const float* b2   = (const float*)d_in[15];
    const float* Wg   = (const float*)d_in[16];
    const float* bg   = (const float*)d_in[17];
    const float* Wp   = (const float*)d_in[18];
    const float* bp   = (const float*)d_in[19];
    const float* gn   = (const float*)d_in[20];
    const float* bnb  = (const float*)d_in[21];

    // output aliasing: x state = out-x region; z plane B = out-z region
    float* Xf = (float*)d_out;              // [N,64]
    float* B  = (float*)d_out + 3200000;    // [N,128] final z

    // workspace (~43 MB)
    float* A    = (float*)d_ws;                 // fp32 z plane [N][128], 25.6 MB
    float* Hf   = A + 6400000;                  // [N,64] fp32, 12.8 MB
    double* stats = (double*)(Hf + 3200000);    // 256 doubles
    double* s1 = stats, *q1 = stats + 64, *s2 = stats + 128, *q2 = stats + 192;
    float* phiA = (float*)(stats + 256);        // 16384 floats
    int* rowptr = (int*)(phiA + 16384);         // NN+1
    int* deg    = rowptr + NN + 1;
    int* bsum   = deg + NN;
    int* boff   = bsum + 256;
    int* cursor = boff + 256;
    u32* sb     = (u32*)(cursor + NN);          // EE
    int* eeo    = (int*)(sb + EE);              // EE

    const int NB_N = (NN + 255) / 256;
    const int NB_E = (EE + 255) / 256;

    k_init<<<1024, 256, 0, stream>>>(x, Xf, deg, cursor);
    k_phi<<<LL * 32, 128, 0, stream>>>(Lam, We1, be1, phiA);
    k_hist<<<NB_E, 256, 0, stream>>>(ei, deg);
    k_scan1<<<NB_N, 256, 0, stream>>>(deg, rowptr, bsum);
    k_scan2<<<1, 256, 0, stream>>>(bsum, boff, rowptr, NB_N);
    k_scan3<<<NB_N, 256, 0, stream>>>(rowptr, boff);
    k_scatter<<<NB_E, 256, 0, stream>>>(ei, batch, rowptr, cursor, sb, eeo);

    for (int l = 0; l < LL; l++) {
        const float* WeeL = Wee + l * 1024;
        const float* beeL = bee + l * 64;
        const float* WgL  = Wg + l * 1024;
        const float* bgL  = bg + l * 16;
        const float* WpL  = Wp + l * 256;
        const float* bpL  = bp + l * 16;
        const float* phiL = phiA + l * 4096;
        // z plane schedule: l0: pe -> A, l1: A -> B(out), l2: B -> A, l3: A -> B(out, final)
        if (l == 0)
            k_edge<0><<<2048, 256, 0, stream>>>(nullptr, pe, Xf, eat, rowptr, sb, eeo,
                                                phiL, WeeL, beeL, WgL, bgL, WpL, bpL,
                                                Hf, A, stats);
        else if (l == 2)
            k_edge<1><<<2048, 256, 0, stream>>>(B, pe, Xf, eat, rowptr, sb, eeo,
                                                phiL, WeeL, beeL, WgL, bgL, WpL, bpL,
                                                Hf, A, stats);
        else  // l == 1 or l == 3
            k_edge<1><<<2048, 256, 0, stream>>>(A, pe, Xf, eat, rowptr, sb, eeo,
                                                phiL, WeeL, beeL, WgL, bgL, WpL, bpL,
                                                Hf, B, stats);
        k_gemm1<<<512, 256, 0, stream>>>(Hf, W1 + l * 4096, b1 + l * 64, s1, q1);
        k_gemm2<<<512, 256, 0, stream>>>(Hf, W2 + l * 4096, b2 + l * 64,
                                         g1 + l * 64, bt1 + l * 64, s1, q1, s2, q2);
        k_bnout<<<1024, 256, 0, stream>>>(Hf, Xf, s2, q2, gn + l * 64, bnb + l * 64,
                                          (l == LL - 1) ? 0 : 1);
    }
}